// Round 1
// 641.095 us; speedup vs baseline: 1.1936x; 1.1936x over previous
//
#include <hip/hip_runtime.h>
#include <stdint.h>

// B=4, T=4096, D=1024, M=1024.  I/O fp32.  Round 6: replace all 128^2
// 2-barrier GEMMs with a single 256^2-tile 8-phase counted-vmcnt template
// (T2 XOR-swizzle + T3/T4 counted vmcnt + T5 setprio).  gated_bb is split
// into gate-GEMM (MODE 0) + multiply-GEMM (MODE 2, element-wise in-place).
// ffn_wo gets a late bf16 pre-convert into dead cL/cP scratch so the final
// GEMM also uses global_load_lds staging.

#define R_ROWS 16384
#define DIM    1024
#define MDIM   1024
#define TSEQ   4096
#define NCHUNK 64
#define TCH    64

typedef __attribute__((ext_vector_type(8))) short  bf16x8;
typedef __attribute__((ext_vector_type(8))) ushort u16x8;
typedef __attribute__((ext_vector_type(4))) float  f32x4;

__device__ __forceinline__ float bf2f(ushort u) {
  union { float f; unsigned int i; } x; x.i = ((unsigned int)u) << 16; return x.f;
}
__device__ __forceinline__ ushort f2bf(float f) {
  union { float f; unsigned int i; } x; x.f = f;
  unsigned int r = x.i + 0x7fffu + ((x.i >> 16) & 1u);
  return (ushort)(r >> 16);
}
__device__ __forceinline__ float sigmoidf_(float x) {
  return 1.0f / (1.0f + __expf(-x));
}
__device__ __forceinline__ void load_lds16(const void* g, void* s) {
  __builtin_amdgcn_global_load_lds(
      (const __attribute__((address_space(1))) void*)g,
      (__attribute__((address_space(3))) void*)s, 16, 0, 0);
}

// ------------- weight pre-convert: 7 matrices of 1M fp32 -> bf16 ------------
__global__ __launch_bounds__(256)
void cvt_weights(const float* __restrict__ w0, const float* __restrict__ w1,
                 const float* __restrict__ w2, const float* __restrict__ w3,
                 const float* __restrict__ w4, const float* __restrict__ w5,
                 const float* __restrict__ w6, ushort* __restrict__ dst)
{
  const float* src;
  switch (blockIdx.y) {
    case 0: src = w0; break; case 1: src = w1; break;
    case 2: src = w2; break; case 3: src = w3; break;
    case 4: src = w4; break; case 5: src = w5; break;
    default: src = w6; break;
  }
  const int i = blockIdx.x * 256 + threadIdx.x;           // [0, 262144)
  const size_t off = (size_t)blockIdx.y * 1048576 + (size_t)i * 4;
  const float4 v = *(const float4*)(src + (size_t)i * 4);
  ushort4 o; o.x = f2bf(v.x); o.y = f2bf(v.y); o.z = f2bf(v.z); o.w = f2bf(v.w);
  *(ushort4*)(dst + off) = o;
}

// single-matrix fp32 -> bf16 (ffn_wo, launched after linrec frees cL/cP)
__global__ __launch_bounds__(256)
void cvt_one(const float* __restrict__ src, ushort* __restrict__ dst)
{
  const int i = blockIdx.x * 256 + threadIdx.x;           // [0, 262144)
  const float4 v = *(const float4*)(src + (size_t)i * 4);
  ushort4 o; o.x = f2bf(v.x); o.y = f2bf(v.y); o.z = f2bf(v.z); o.w = f2bf(v.w);
  *(ushort4*)(dst + (size_t)i * 4) = o;
}

// ---------------- RMSNorm: one block per row of 1024 -> bf16 out ------------
template<bool IN_F32>
__global__ __launch_bounds__(256)
void rmsnorm_k(const void* __restrict__ xin, const float* __restrict__ w,
               ushort* __restrict__ y)
{
  __shared__ float red[4];
  const int row = blockIdx.x;
  const int tid = threadIdx.x;
  const size_t base = (size_t)row * DIM + tid * 4;
  float v[4];
  if (IN_F32) {
    const float4 xv = *(const float4*)((const float*)xin + base);
    v[0] = xv.x; v[1] = xv.y; v[2] = xv.z; v[3] = xv.w;
  } else {
    const ushort4 xv = *(const ushort4*)((const ushort*)xin + base);
    v[0] = bf2f(xv.x); v[1] = bf2f(xv.y); v[2] = bf2f(xv.z); v[3] = bf2f(xv.w);
  }
  float ss = v[0]*v[0] + v[1]*v[1] + v[2]*v[2] + v[3]*v[3];
  for (int o = 32; o > 0; o >>= 1) ss += __shfl_down(ss, o, 64);
  const int wave = tid >> 6, lane = tid & 63;
  if (lane == 0) red[wave] = ss;
  __syncthreads();
  const float sum = red[0] + red[1] + red[2] + red[3];
  const float scale = rsqrtf(sum * (1.0f / DIM) + 1e-6f);
  const float4 wv = *(const float4*)(w + tid * 4);
  ushort4 o4;
  o4.x = f2bf(v[0] * scale * wv.x);
  o4.y = f2bf(v[1] * scale * wv.y);
  o4.z = f2bf(v[2] * scale * wv.z);
  o4.w = f2bf(v[3] * scale * wv.w);
  *(ushort4*)(y + base) = o4;
}

// ======================= 256^2 8-phase bf16 GEMM ===========================
// C[r,n] = sum_k A[r,k] * W[n,k].  256x256 tile, BK=64, 8 waves (2M x 4N),
// 512 threads, LDS 128 KiB = 2 buf x {A,B} x 2 halves x [128][64] bf16.
// Per-wave output 128x64 (8x4 16x16 fragments).  K = 1024 -> 16 K-tiles.
//
// Swizzle (T2): within a row (64 bf16 = 8 x 16B chunks), logical chunk c
// lives in LDS chunk c ^ (row&7).  global_load_lds writes LDS linearly, so
// the GLOBAL source chunk for LDS slot c8 is c8 ^ (row&7); ds_read applies
// the same XOR.  -> 8 lanes/bank = b128 floor, conflict-free.
//
// Schedule (T3/T4): group computing K-tile kt from buf kt&1, 4 phases:
//   ph0: read b-frags(8) + a-frags(4); stage A0(kt+1)
//   ph1: read a-frags(4);              stage A1(kt+1)
//   ph2: read a-frags(4);              stage B0(kt+2)
//   ph3: read a-frags(4);              stage B1(kt+2); vmcnt(4)
// each phase: barrier; lgkmcnt(0); setprio(1); 16 MFMA; setprio(0); barrier.
// Liveness: A(kt+1) overwrites A(kt-1) (dead since prev group end barrier);
// B(kt+2) overwrites B(kt) (dead after ph0's 2nd barrier).  vmcnt(4) at
// group end forces tile kt+1 landed with exactly B(kt+2) (4 loads) in
// flight; last two groups use vmcnt(0).
//
// MODE 0: out bf16 = sigmoid(v + bias[col])
// MODE 1: out bf16 = v + auxf[idx]          (fp32 aux)
// MODE 2: out bf16 = v * bf2f(auxb[idx])    (element-wise, in-place safe)
// MODE 3: out fp32 = v + bf2f(auxb[idx])
template<int MODE>
__global__ __launch_bounds__(512, 2)
void gemm8(const ushort* __restrict__ A, const ushort* __restrict__ W,
           const float* __restrict__ bias, const float* __restrict__ auxf,
           const ushort* __restrict__ auxb, ushort* __restrict__ outb,
           float* __restrict__ outf)
{
  __shared__ __align__(16) ushort lds[2][2][2][8192]; // [buf][A/B][half][128*64]
  const int tid  = threadIdx.x;
  const int bm = blockIdx.x, bn = blockIdx.y;
  const int wave = tid >> 6, lane = tid & 63;
  const int wm = wave >> 2, wn = wave & 3;            // 2M x 4N waves
  const int quad = lane >> 4, l16 = lane & 15;
  const int axor = l16 & 7;                           // row&7 for all our reads

  const ushort* Ab = A + (size_t)bm * (256 * 1024);
  const ushort* Wb = W + (size_t)bn * (256 * 1024);

  f32x4 acc[8][4];
#pragma unroll
  for (int i = 0; i < 8; ++i)
#pragma unroll
    for (int j = 0; j < 4; ++j) acc[i][j] = (f32x4){0.f, 0.f, 0.f, 0.f};

  // stage one half-tile (128 rows x 64 k): 2 x global_load_lds per thread.
  auto stage = [&](const ushort* __restrict__ base, int kt, int mat, int half) {
    ushort* dst = &lds[kt & 1][mat][half][0];
    const ushort* src = base + (size_t)half * (128 * 1024) + kt * 64;
#pragma unroll
    for (int q = 0; q < 2; ++q) {
      const int ci = q * 512 + tid;                   // 0..1023
      const int row = ci >> 3, c8 = ci & 7;
      load_lds16(src + (size_t)row * 1024 + ((c8 ^ (row & 7)) << 3),
                 dst + ci * 8);
    }
  };

  // prologue: kt0 {A0,A1,B0,B1}, kt1 {B0,B1}; vmcnt(4) -> kt0 landed.
  stage(Ab, 0, 0, 0); stage(Ab, 0, 0, 1);
  stage(Wb, 0, 1, 0); stage(Wb, 0, 1, 1);
  stage(Wb, 1, 1, 0); stage(Wb, 1, 1, 1);
  asm volatile("s_waitcnt vmcnt(4)" ::: "memory");
  __builtin_amdgcn_s_barrier();

  for (int ktc = 0; ktc < 16; ++ktc) {
    const int b = ktc & 1;
    const ushort* Ah = &lds[b][0][wm][0];
    const ushort* Bh = &lds[b][1][wn >> 1][0];
    const int brow0 = (wn & 1) * 64;
    bf16x8 bfr[4][2];
#pragma unroll
    for (int q = 0; q < 4; ++q) {
      if (q == 0) {
#pragma unroll
        for (int j = 0; j < 4; ++j)
#pragma unroll
          for (int ks = 0; ks < 2; ++ks)
            bfr[j][ks] = *(const bf16x8*)
                &Bh[(brow0 + j * 16 + l16) * 64 +
                    (((ks * 4 + quad) ^ axor) << 3)];
      }
      bf16x8 af[2][2];
#pragma unroll
      for (int p = 0; p < 2; ++p)
#pragma unroll
        for (int ks = 0; ks < 2; ++ks)
          af[p][ks] = *(const bf16x8*)
              &Ah[((2 * q + p) * 16 + l16) * 64 +
                  (((ks * 4 + quad) ^ axor) << 3)];
      if (q == 0 && ktc + 1 < 16) stage(Ab, ktc + 1, 0, 0);
      if (q == 1 && ktc + 1 < 16) stage(Ab, ktc + 1, 0, 1);
      if (q == 2 && ktc + 2 < 16) stage(Wb, ktc + 2, 1, 0);
      if (q == 3 && ktc + 2 < 16) stage(Wb, ktc + 2, 1, 1);
      __builtin_amdgcn_s_barrier();
      asm volatile("s_waitcnt lgkmcnt(0)" ::: "memory");
      __builtin_amdgcn_s_setprio(1);
#pragma unroll
      for (int p = 0; p < 2; ++p)
#pragma unroll
        for (int j = 0; j < 4; ++j)
#pragma unroll
          for (int ks = 0; ks < 2; ++ks)
            acc[2 * q + p][j] = __builtin_amdgcn_mfma_f32_16x16x32_bf16(
                af[p][ks], bfr[j][ks], acc[2 * q + p][j], 0, 0, 0);
      __builtin_amdgcn_s_setprio(0);
      if (q == 3) {
        if (ktc >= 14) asm volatile("s_waitcnt vmcnt(0)" ::: "memory");
        else           asm volatile("s_waitcnt vmcnt(4)" ::: "memory");
      }
      __builtin_amdgcn_s_barrier();
    }
  }

  // epilogue
  const int rbase = bm * 256 + wm * 128 + quad * 4;
  const int cbase = bn * 256 + wn * 64 + l16;
#pragma unroll
  for (int j = 0; j < 4; ++j) {
    const int col = cbase + j * 16;
    const float bv = (MODE == 0) ? bias[col] : 0.f;
#pragma unroll
    for (int i = 0; i < 8; ++i) {
#pragma unroll
      for (int g = 0; g < 4; ++g) {
        const size_t idx = (size_t)(rbase + i * 16 + g) * 1024 + col;
        const float v = acc[i][j][g];
        if (MODE == 0)      outb[idx] = f2bf(sigmoidf_(v + bv));
        else if (MODE == 1) outb[idx] = f2bf(v + auxf[idx]);
        else if (MODE == 2) outb[idx] = f2bf(v * bf2f(auxb[idx]));
        else                outf[idx] = v + bf2f(auxb[idx]);
      }
    }
  }
}

// ------------- linear recurrence h_t = xg_t + r_t*h_{t-1}, chunked ----------
__global__ __launch_bounds__(256)
void linrec_passA(ushort* __restrict__ xg, const ushort* __restrict__ r,
                  float* __restrict__ cL, float* __restrict__ cP)
{
  const int g = blockIdx.x * 256 + threadIdx.x;   // [0, 262144)
  const int m = g & (MDIM - 1);
  const int bc = g >> 10;
  const int b = bc >> 6, c = bc & 63;
  const size_t base = ((size_t)(b * TSEQ + c * TCH)) * MDIM + m;
  float h = 0.f, p = 1.f;
  for (int t = 0; t < TCH; ++t) {
    const size_t idx = base + (size_t)t * MDIM;
    const float xv = bf2f(xg[idx]), rv = bf2f(r[idx]);
    h = fmaf(rv, h, xv);
    p *= rv;
    xg[idx] = f2bf(h);       // local prefix (chunk-start state 0), in place
  }
  cL[c * 4096 + b * MDIM + m] = h;
  cP[c * 4096 + b * MDIM + m] = p;
}

__global__ __launch_bounds__(256)
void linrec_passB(const float* __restrict__ cL, const float* __restrict__ cP,
                  const float* __restrict__ mem, float* __restrict__ cIn,
                  float* __restrict__ memout)
{
  const int g = blockIdx.x * 256 + threadIdx.x;   // [0,4096)
  float carry = mem[g];
  for (int c = 0; c < NCHUNK; ++c) {
    cIn[c * 4096 + g] = carry;
    carry = fmaf(cP[c * 4096 + g], carry, cL[c * 4096 + g]);
  }
  memout[g] = carry;
}

__global__ __launch_bounds__(256)
void linrec_passC(const ushort* __restrict__ L, const ushort* __restrict__ r,
                  const ushort* __restrict__ og, const float* __restrict__ cIn,
                  ushort* __restrict__ s)
{
  const int g = blockIdx.x * 256 + threadIdx.x;
  const int m = g & (MDIM - 1);
  const int bc = g >> 10;
  const int b = bc >> 6, c = bc & 63;
  const size_t base = ((size_t)(b * TSEQ + c * TCH)) * MDIM + m;
  const float cin = cIn[c * 4096 + b * MDIM + m];
  float p = 1.f;
  for (int t = 0; t < TCH; ++t) {
    const size_t idx = base + (size_t)t * MDIM;
    p *= bf2f(r[idx]);
    const float h = fmaf(p, cin, bf2f(L[idx]));
    const float sv = h / (1.0f + fabsf(h)) * bf2f(og[idx]);
    s[idx] = f2bf(sv);
  }
}

// ---------------- launch ----------------
extern "C" void kernel_launch(void* const* d_in, const int* in_sizes, int n_in,
                              void* d_out, int out_size, void* d_ws, size_t ws_size,
                              hipStream_t stream)
{
  const float* x        = (const float*)d_in[0];
  const float* mem      = (const float*)d_in[1];
  const float* norm_w   = (const float*)d_in[2];
  const float* wr_w     = (const float*)d_in[3];
  const float* wr_b     = (const float*)d_in[4];
  const float* wi_w     = (const float*)d_in[5];
  const float* wig_w    = (const float*)d_in[6];
  const float* wig_b    = (const float*)d_in[7];
  const float* wog_w    = (const float*)d_in[8];
  const float* wog_b    = (const float*)d_in[9];
  const float* wo_w     = (const float*)d_in[10];
  const float* ffnorm_w = (const float*)d_in[11];
  const float* ffn_wi_w = (const float*)d_in[12];
  const float* ffn_wg_w = (const float*)d_in[13];
  const float* ffn_wg_b = (const float*)d_in[14];
  const float* ffn_wo_w = (const float*)d_in[15];
  float* outF = (float*)d_out;

  // d_out scratch (dead until final GEMM / passB):
  ushort* xgL  = (ushort*)d_out;                        // [0,32MB): ig -> xg -> L
  ushort* wbf  = (ushort*)((char*)d_out + 33554432ULL); // [32,46MB): 7x bf16 W
  float*  memoutF = outF + 16777216;                    // mem_out fp32

  // ws (~99MB, same footprint as round 5):
  char* ws = (char*)d_ws;
  ushort* y   = (ushort*)(ws);                 // 32MB bf16: y -> s -> gf/ff
  ushort* r   = (ushort*)(ws + 33554432ULL);   // 32MB bf16: r -> z
  ushort* og  = (ushort*)(ws + 67108864ULL);   // 32MB bf16: og -> x1
  float*  cL  = (float*) (ws + 100663296ULL);  // 1MB (dead after passB)
  float*  cP  = (float*) (ws + 101711872ULL);  // 1MB (dead after passB)
  float*  cIn = (float*) (ws + 102760448ULL);  // 1MB
  ushort* s   = y;
  ushort* x1  = og;
  ushort* z   = r;
  ushort* gf  = y;                             // ffn gate -> ff (in-place)
  // ffn_wo bf16 (2MB) reuses cL+cP after linrec:
  ushort* fwo_bf = (ushort*)(ws + 100663296ULL);

  // bf16 weight slots (1M elems each): 0=wr 1=wog 2=wi 3=wig 4=wo 5=ffn_wi 6=ffn_wg
  ushort* wr_bf   = wbf + 0 * 1048576;
  ushort* wog_bf  = wbf + 1 * 1048576;
  ushort* wi_bf   = wbf + 2 * 1048576;
  ushort* wig_bf  = wbf + 3 * 1048576;
  ushort* wo_bf   = wbf + 4 * 1048576;
  ushort* fwi_bf  = wbf + 5 * 1048576;
  ushort* fwg_bf  = wbf + 6 * 1048576;

  const dim3 g8(64, 4);   // 16384/256 x 1024/256

  cvt_weights<<<dim3(1024, 7), 256, 0, stream>>>(
      wr_w, wog_w, wi_w, wig_w, wo_w, ffn_wi_w, ffn_wg_w, wbf);

  // sqrll branch
  rmsnorm_k<true><<<R_ROWS, 256, 0, stream>>>(x, norm_w, y);
  gemm8<0><<<g8, 512, 0, stream>>>(y, wr_bf,  wr_b,  nullptr, nullptr, r,   nullptr);
  gemm8<0><<<g8, 512, 0, stream>>>(y, wog_bf, wog_b, nullptr, nullptr, og,  nullptr);
  gemm8<0><<<g8, 512, 0, stream>>>(y, wig_bf, wig_b, nullptr, nullptr, xgL, nullptr); // ig
  gemm8<2><<<g8, 512, 0, stream>>>(y, wi_bf,  nullptr, nullptr, xgL, xgL, nullptr);   // xg=ig*(y.wi)
  linrec_passA<<<1024, 256, 0, stream>>>(xgL, r, cL, cP);
  linrec_passB<<<16, 256, 0, stream>>>(cL, cP, mem, cIn, memoutF);
  linrec_passC<<<1024, 256, 0, stream>>>(xgL, r, og, cIn, s);
  cvt_one<<<1024, 256, 0, stream>>>(ffn_wo_w, fwo_bf);     // cL/cP now dead
  gemm8<1><<<g8, 512, 0, stream>>>(s, wo_bf, nullptr, x, nullptr, x1, nullptr);
  // ffn branch
  rmsnorm_k<false><<<R_ROWS, 256, 0, stream>>>(x1, ffnorm_w, z);
  gemm8<0><<<g8, 512, 0, stream>>>(z, fwg_bf, ffn_wg_b, nullptr, nullptr, gf, nullptr);
  gemm8<2><<<g8, 512, 0, stream>>>(z, fwi_bf, nullptr, nullptr, gf, gf, nullptr);     // ff
  gemm8<3><<<g8, 512, 0, stream>>>(gf, fwo_bf, nullptr, nullptr, x1, nullptr, outF);
}

// Round 2
// 569.507 us; speedup vs baseline: 1.3436x; 1.1257x over previous
//
#include <hip/hip_runtime.h>
#include <stdint.h>

// B=4, T=4096, D=1024, M=1024.  I/O fp32.  Round 7: keep the 256^2 8-phase
// counted-vmcnt GEMM main loop (round 6), replace the scattered 2B-store
// epilogue with an LDS-transposed coalesced epilogue (fp32, 2 half-tile
// passes, aux/bias applied at read time -> numerics unchanged).  Vectorize
// linrec passA/passC to ushort4 (4 m per thread).

#define R_ROWS 16384
#define DIM    1024
#define MDIM   1024
#define TSEQ   4096
#define NCHUNK 64
#define TCH    64

typedef __attribute__((ext_vector_type(8))) short  bf16x8;
typedef __attribute__((ext_vector_type(8))) ushort u16x8;
typedef __attribute__((ext_vector_type(4))) float  f32x4;

__device__ __forceinline__ float bf2f(ushort u) {
  union { float f; unsigned int i; } x; x.i = ((unsigned int)u) << 16; return x.f;
}
__device__ __forceinline__ ushort f2bf(float f) {
  union { float f; unsigned int i; } x; x.f = f;
  unsigned int r = x.i + 0x7fffu + ((x.i >> 16) & 1u);
  return (ushort)(r >> 16);
}
__device__ __forceinline__ float sigmoidf_(float x) {
  return 1.0f / (1.0f + __expf(-x));
}
__device__ __forceinline__ void load_lds16(const void* g, void* s) {
  __builtin_amdgcn_global_load_lds(
      (const __attribute__((address_space(1))) void*)g,
      (__attribute__((address_space(3))) void*)s, 16, 0, 0);
}

// ------------- weight pre-convert: 7 matrices of 1M fp32 -> bf16 ------------
__global__ __launch_bounds__(256)
void cvt_weights(const float* __restrict__ w0, const float* __restrict__ w1,
                 const float* __restrict__ w2, const float* __restrict__ w3,
                 const float* __restrict__ w4, const float* __restrict__ w5,
                 const float* __restrict__ w6, ushort* __restrict__ dst)
{
  const float* src;
  switch (blockIdx.y) {
    case 0: src = w0; break; case 1: src = w1; break;
    case 2: src = w2; break; case 3: src = w3; break;
    case 4: src = w4; break; case 5: src = w5; break;
    default: src = w6; break;
  }
  const int i = blockIdx.x * 256 + threadIdx.x;           // [0, 262144)
  const size_t off = (size_t)blockIdx.y * 1048576 + (size_t)i * 4;
  const float4 v = *(const float4*)(src + (size_t)i * 4);
  ushort4 o; o.x = f2bf(v.x); o.y = f2bf(v.y); o.z = f2bf(v.z); o.w = f2bf(v.w);
  *(ushort4*)(dst + off) = o;
}

// single-matrix fp32 -> bf16 (ffn_wo, launched after linrec frees cL/cP)
__global__ __launch_bounds__(256)
void cvt_one(const float* __restrict__ src, ushort* __restrict__ dst)
{
  const int i = blockIdx.x * 256 + threadIdx.x;           // [0, 262144)
  const float4 v = *(const float4*)(src + (size_t)i * 4);
  ushort4 o; o.x = f2bf(v.x); o.y = f2bf(v.y); o.z = f2bf(v.z); o.w = f2bf(v.w);
  *(ushort4*)(dst + (size_t)i * 4) = o;
}

// ---------------- RMSNorm: one block per row of 1024 -> bf16 out ------------
template<bool IN_F32>
__global__ __launch_bounds__(256)
void rmsnorm_k(const void* __restrict__ xin, const float* __restrict__ w,
               ushort* __restrict__ y)
{
  __shared__ float red[4];
  const int row = blockIdx.x;
  const int tid = threadIdx.x;
  const size_t base = (size_t)row * DIM + tid * 4;
  float v[4];
  if (IN_F32) {
    const float4 xv = *(const float4*)((const float*)xin + base);
    v[0] = xv.x; v[1] = xv.y; v[2] = xv.z; v[3] = xv.w;
  } else {
    const ushort4 xv = *(const ushort4*)((const ushort*)xin + base);
    v[0] = bf2f(xv.x); v[1] = bf2f(xv.y); v[2] = bf2f(xv.z); v[3] = bf2f(xv.w);
  }
  float ss = v[0]*v[0] + v[1]*v[1] + v[2]*v[2] + v[3]*v[3];
  for (int o = 32; o > 0; o >>= 1) ss += __shfl_down(ss, o, 64);
  const int wave = tid >> 6, lane = tid & 63;
  if (lane == 0) red[wave] = ss;
  __syncthreads();
  const float sum = red[0] + red[1] + red[2] + red[3];
  const float scale = rsqrtf(sum * (1.0f / DIM) + 1e-6f);
  const float4 wv = *(const float4*)(w + tid * 4);
  ushort4 o4;
  o4.x = f2bf(v[0] * scale * wv.x);
  o4.y = f2bf(v[1] * scale * wv.y);
  o4.z = f2bf(v[2] * scale * wv.z);
  o4.w = f2bf(v[3] * scale * wv.w);
  *(ushort4*)(y + base) = o4;
}

// ======================= 256^2 8-phase bf16 GEMM ===========================
// C[r,n] = sum_k A[r,k] * W[n,k].  256x256 tile, BK=64, 8 waves (2M x 4N),
// 512 threads, LDS 128 KiB = 2 buf x {A,B} x 2 halves x [128][64] bf16.
// Main loop identical to round 6 (T2 XOR-swizzle, counted vmcnt(4), setprio).
//
// Epilogue (NEW): LDS-transposed coalesced stores.  After the K-loop the
// 128 KiB LDS is dead; 2 passes, pass h = rows [h*128, h*128+128):
//   waves wm==h ds_write their fp32 acc into C[128][256] (quad-parity XOR
//   -> max 2-way bank aliasing = free), barrier, then all 512 threads read
//   rows linearly (ds_read_b128) and store 8B bf16 / 16B fp32 per lane,
//   fully line-coalesced.  bias/aux are read coalesced at the same time, so
//   numerics match round 6 exactly (activation applied on fp32).
//
// MODE 0: out bf16 = sigmoid(v + bias[col])
// MODE 1: out bf16 = v + auxf[idx]          (fp32 aux)
// MODE 2: out bf16 = v * bf2f(auxb[idx])    (element-wise, in-place safe)
// MODE 3: out fp32 = v + bf2f(auxb[idx])
template<int MODE>
__global__ __launch_bounds__(512, 2)
void gemm8(const ushort* __restrict__ A, const ushort* __restrict__ W,
           const float* __restrict__ bias, const float* __restrict__ auxf,
           const ushort* __restrict__ auxb, ushort* __restrict__ outb,
           float* __restrict__ outf)
{
  __shared__ __align__(16) ushort lds[2][2][2][8192]; // [buf][A/B][half][128*64]
  const int tid  = threadIdx.x;
  const int bm = blockIdx.x, bn = blockIdx.y;
  const int wave = tid >> 6, lane = tid & 63;
  const int wm = wave >> 2, wn = wave & 3;            // 2M x 4N waves
  const int quad = lane >> 4, l16 = lane & 15;
  const int axor = l16 & 7;                           // row&7 for all our reads

  const ushort* Ab = A + (size_t)bm * (256 * 1024);
  const ushort* Wb = W + (size_t)bn * (256 * 1024);

  f32x4 acc[8][4];
#pragma unroll
  for (int i = 0; i < 8; ++i)
#pragma unroll
    for (int j = 0; j < 4; ++j) acc[i][j] = (f32x4){0.f, 0.f, 0.f, 0.f};

  // stage one half-tile (128 rows x 64 k): 2 x global_load_lds per thread.
  auto stage = [&](const ushort* __restrict__ base, int kt, int mat, int half) {
    ushort* dst = &lds[kt & 1][mat][half][0];
    const ushort* src = base + (size_t)half * (128 * 1024) + kt * 64;
#pragma unroll
    for (int q = 0; q < 2; ++q) {
      const int ci = q * 512 + tid;                   // 0..1023
      const int row = ci >> 3, c8 = ci & 7;
      load_lds16(src + (size_t)row * 1024 + ((c8 ^ (row & 7)) << 3),
                 dst + ci * 8);
    }
  };

  // prologue: kt0 {A0,A1,B0,B1}, kt1 {B0,B1}; vmcnt(4) -> kt0 landed.
  stage(Ab, 0, 0, 0); stage(Ab, 0, 0, 1);
  stage(Wb, 0, 1, 0); stage(Wb, 0, 1, 1);
  stage(Wb, 1, 1, 0); stage(Wb, 1, 1, 1);
  asm volatile("s_waitcnt vmcnt(4)" ::: "memory");
  __builtin_amdgcn_s_barrier();

  for (int ktc = 0; ktc < 16; ++ktc) {
    const int b = ktc & 1;
    const ushort* Ah = &lds[b][0][wm][0];
    const ushort* Bh = &lds[b][1][wn >> 1][0];
    const int brow0 = (wn & 1) * 64;
    bf16x8 bfr[4][2];
#pragma unroll
    for (int q = 0; q < 4; ++q) {
      if (q == 0) {
#pragma unroll
        for (int j = 0; j < 4; ++j)
#pragma unroll
          for (int ks = 0; ks < 2; ++ks)
            bfr[j][ks] = *(const bf16x8*)
                &Bh[(brow0 + j * 16 + l16) * 64 +
                    (((ks * 4 + quad) ^ axor) << 3)];
      }
      bf16x8 af[2][2];
#pragma unroll
      for (int p = 0; p < 2; ++p)
#pragma unroll
        for (int ks = 0; ks < 2; ++ks)
          af[p][ks] = *(const bf16x8*)
              &Ah[((2 * q + p) * 16 + l16) * 64 +
                  (((ks * 4 + quad) ^ axor) << 3)];
      if (q == 0 && ktc + 1 < 16) stage(Ab, ktc + 1, 0, 0);
      if (q == 1 && ktc + 1 < 16) stage(Ab, ktc + 1, 0, 1);
      if (q == 2 && ktc + 2 < 16) stage(Wb, ktc + 2, 1, 0);
      if (q == 3 && ktc + 2 < 16) stage(Wb, ktc + 2, 1, 1);
      __builtin_amdgcn_s_barrier();
      asm volatile("s_waitcnt lgkmcnt(0)" ::: "memory");
      __builtin_amdgcn_s_setprio(1);
#pragma unroll
      for (int p = 0; p < 2; ++p)
#pragma unroll
        for (int j = 0; j < 4; ++j)
#pragma unroll
          for (int ks = 0; ks < 2; ++ks)
            acc[2 * q + p][j] = __builtin_amdgcn_mfma_f32_16x16x32_bf16(
                af[p][ks], bfr[j][ks], acc[2 * q + p][j], 0, 0, 0);
      __builtin_amdgcn_s_setprio(0);
      if (q == 3) {
        if (ktc >= 14) asm volatile("s_waitcnt vmcnt(0)" ::: "memory");
        else           asm volatile("s_waitcnt vmcnt(4)" ::: "memory");
      }
      __builtin_amdgcn_s_barrier();
    }
  }

  // ---------------- coalesced LDS-transposed epilogue ----------------
  float* C = (float*)&lds[0][0][0][0];                // [128][256] fp32
#pragma unroll 1
  for (int h = 0; h < 2; ++h) {
    if (wm == h) {
      const int cb = wn * 64;
#pragma unroll
      for (int i = 0; i < 8; ++i)
#pragma unroll
        for (int j = 0; j < 4; ++j)
#pragma unroll
          for (int g = 0; g < 4; ++g) {
            const int rw = i * 16 + quad * 4 + g;
            const int cw = cb + j * 16 + l16;
            C[rw * 256 + (cw ^ (((rw >> 2) & 1) << 4))] = acc[i][j][g];
          }
    }
    __syncthreads();
#pragma unroll 1
    for (int sp = 0; sp < 16; ++sp) {
      const int lin = sp * 2048 + tid * 4;
      const int row = lin >> 8, c4 = lin & 255;
      const int xr = ((row >> 2) & 1) << 4;
      const float4 v4 = *(const float4*)&C[row * 256 + (c4 ^ xr)];
      const int rg = bm * 256 + h * 128 + row;
      const int cg = bn * 256 + c4;
      const size_t gidx = (size_t)rg * 1024 + cg;
      if (MODE == 0) {
        const float4 bv = *(const float4*)(bias + cg);
        ushort4 o;
        o.x = f2bf(sigmoidf_(v4.x + bv.x));
        o.y = f2bf(sigmoidf_(v4.y + bv.y));
        o.z = f2bf(sigmoidf_(v4.z + bv.z));
        o.w = f2bf(sigmoidf_(v4.w + bv.w));
        *(ushort4*)(outb + gidx) = o;
      } else if (MODE == 1) {
        const float4 a4 = *(const float4*)(auxf + gidx);
        ushort4 o;
        o.x = f2bf(v4.x + a4.x); o.y = f2bf(v4.y + a4.y);
        o.z = f2bf(v4.z + a4.z); o.w = f2bf(v4.w + a4.w);
        *(ushort4*)(outb + gidx) = o;
      } else if (MODE == 2) {
        const ushort4 a4 = *(const ushort4*)(auxb + gidx);
        ushort4 o;
        o.x = f2bf(v4.x * bf2f(a4.x)); o.y = f2bf(v4.y * bf2f(a4.y));
        o.z = f2bf(v4.z * bf2f(a4.z)); o.w = f2bf(v4.w * bf2f(a4.w));
        *(ushort4*)(outb + gidx) = o;
      } else {
        const ushort4 a4 = *(const ushort4*)(auxb + gidx);
        float4 o;
        o.x = v4.x + bf2f(a4.x); o.y = v4.y + bf2f(a4.y);
        o.z = v4.z + bf2f(a4.z); o.w = v4.w + bf2f(a4.w);
        *(float4*)(outf + gidx) = o;
      }
    }
    __syncthreads();
  }
}

// ------------- linear recurrence h_t = xg_t + r_t*h_{t-1}, chunked ----------
// 4 consecutive m per thread -> ushort4 (8B/lane) loads/stores.
__global__ __launch_bounds__(256)
void linrec_passA(ushort* __restrict__ xg, const ushort* __restrict__ r,
                  float* __restrict__ cL, float* __restrict__ cP)
{
  const int g = blockIdx.x * 256 + threadIdx.x;   // [0, 65536)
  const int m4 = (g & 255) << 2;
  const int bc = g >> 8;
  const int b = bc >> 6, c = bc & 63;
  const size_t base = ((size_t)(b * TSEQ + c * TCH)) * MDIM + m4;
  float h0 = 0.f, h1 = 0.f, h2 = 0.f, h3 = 0.f;
  float p0 = 1.f, p1 = 1.f, p2 = 1.f, p3 = 1.f;
  for (int t = 0; t < TCH; ++t) {
    const size_t idx = base + (size_t)t * MDIM;
    const ushort4 xv = *(const ushort4*)&xg[idx];
    const ushort4 rv = *(const ushort4*)&r[idx];
    const float r0 = bf2f(rv.x), r1 = bf2f(rv.y), r2 = bf2f(rv.z), r3 = bf2f(rv.w);
    h0 = fmaf(r0, h0, bf2f(xv.x)); p0 *= r0;
    h1 = fmaf(r1, h1, bf2f(xv.y)); p1 *= r1;
    h2 = fmaf(r2, h2, bf2f(xv.z)); p2 *= r2;
    h3 = fmaf(r3, h3, bf2f(xv.w)); p3 *= r3;
    ushort4 o; o.x = f2bf(h0); o.y = f2bf(h1); o.z = f2bf(h2); o.w = f2bf(h3);
    *(ushort4*)&xg[idx] = o;   // local prefix (chunk-start state 0), in place
  }
  const size_t cb = (size_t)c * 4096 + b * MDIM + m4;
  float4 L4; L4.x = h0; L4.y = h1; L4.z = h2; L4.w = h3;
  float4 P4; P4.x = p0; P4.y = p1; P4.z = p2; P4.w = p3;
  *(float4*)&cL[cb] = L4;
  *(float4*)&cP[cb] = P4;
}

__global__ __launch_bounds__(256)
void linrec_passB(const float* __restrict__ cL, const float* __restrict__ cP,
                  const float* __restrict__ mem, float* __restrict__ cIn,
                  float* __restrict__ memout)
{
  const int g = blockIdx.x * 256 + threadIdx.x;   // [0,4096)
  float carry = mem[g];
  for (int c = 0; c < NCHUNK; ++c) {
    cIn[c * 4096 + g] = carry;
    carry = fmaf(cP[c * 4096 + g], carry, cL[c * 4096 + g]);
  }
  memout[g] = carry;
}

__global__ __launch_bounds__(256)
void linrec_passC(const ushort* __restrict__ L, const ushort* __restrict__ r,
                  const ushort* __restrict__ og, const float* __restrict__ cIn,
                  ushort* __restrict__ s)
{
  const int g = blockIdx.x * 256 + threadIdx.x;   // [0, 65536)
  const int m4 = (g & 255) << 2;
  const int bc = g >> 8;
  const int b = bc >> 6, c = bc & 63;
  const size_t base = ((size_t)(b * TSEQ + c * TCH)) * MDIM + m4;
  const size_t cb = (size_t)c * 4096 + b * MDIM + m4;
  const float4 ci = *(const float4*)&cIn[cb];
  float p0 = 1.f, p1 = 1.f, p2 = 1.f, p3 = 1.f;
  for (int t = 0; t < TCH; ++t) {
    const size_t idx = base + (size_t)t * MDIM;
    const ushort4 rv = *(const ushort4*)&r[idx];
    const ushort4 lv = *(const ushort4*)&L[idx];
    const ushort4 ov = *(const ushort4*)&og[idx];
    p0 *= bf2f(rv.x); p1 *= bf2f(rv.y); p2 *= bf2f(rv.z); p3 *= bf2f(rv.w);
    const float a0 = fmaf(p0, ci.x, bf2f(lv.x));
    const float a1 = fmaf(p1, ci.y, bf2f(lv.y));
    const float a2 = fmaf(p2, ci.z, bf2f(lv.z));
    const float a3 = fmaf(p3, ci.w, bf2f(lv.w));
    ushort4 o;
    o.x = f2bf(a0 / (1.0f + fabsf(a0)) * bf2f(ov.x));
    o.y = f2bf(a1 / (1.0f + fabsf(a1)) * bf2f(ov.y));
    o.z = f2bf(a2 / (1.0f + fabsf(a2)) * bf2f(ov.z));
    o.w = f2bf(a3 / (1.0f + fabsf(a3)) * bf2f(ov.w));
    *(ushort4*)&s[idx] = o;
  }
}

// ---------------- launch ----------------
extern "C" void kernel_launch(void* const* d_in, const int* in_sizes, int n_in,
                              void* d_out, int out_size, void* d_ws, size_t ws_size,
                              hipStream_t stream)
{
  const float* x        = (const float*)d_in[0];
  const float* mem      = (const float*)d_in[1];
  const float* norm_w   = (const float*)d_in[2];
  const float* wr_w     = (const float*)d_in[3];
  const float* wr_b     = (const float*)d_in[4];
  const float* wi_w     = (const float*)d_in[5];
  const float* wig_w    = (const float*)d_in[6];
  const float* wig_b    = (const float*)d_in[7];
  const float* wog_w    = (const float*)d_in[8];
  const float* wog_b    = (const float*)d_in[9];
  const float* wo_w     = (const float*)d_in[10];
  const float* ffnorm_w = (const float*)d_in[11];
  const float* ffn_wi_w = (const float*)d_in[12];
  const float* ffn_wg_w = (const float*)d_in[13];
  const float* ffn_wg_b = (const float*)d_in[14];
  const float* ffn_wo_w = (const float*)d_in[15];
  float* outF = (float*)d_out;

  // d_out scratch (dead until final GEMM / passB):
  ushort* xgL  = (ushort*)d_out;                        // [0,32MB): ig -> xg -> L
  ushort* wbf  = (ushort*)((char*)d_out + 33554432ULL); // [32,46MB): 7x bf16 W
  float*  memoutF = outF + 16777216;                    // mem_out fp32

  // ws (~99MB):
  char* ws = (char*)d_ws;
  ushort* y   = (ushort*)(ws);                 // 32MB bf16: y -> s -> gf/ff
  ushort* r   = (ushort*)(ws + 33554432ULL);   // 32MB bf16: r -> z
  ushort* og  = (ushort*)(ws + 67108864ULL);   // 32MB bf16: og -> x1
  float*  cL  = (float*) (ws + 100663296ULL);  // 1MB (dead after passB)
  float*  cP  = (float*) (ws + 101711872ULL);  // 1MB (dead after passB)
  float*  cIn = (float*) (ws + 102760448ULL);  // 1MB
  ushort* s   = y;
  ushort* x1  = og;
  ushort* z   = r;
  ushort* gf  = y;                             // ffn gate -> ff (in-place)
  // ffn_wo bf16 (2MB) reuses cL+cP after linrec:
  ushort* fwo_bf = (ushort*)(ws + 100663296ULL);

  // bf16 weight slots (1M elems each): 0=wr 1=wog 2=wi 3=wig 4=wo 5=ffn_wi 6=ffn_wg
  ushort* wr_bf   = wbf + 0 * 1048576;
  ushort* wog_bf  = wbf + 1 * 1048576;
  ushort* wi_bf   = wbf + 2 * 1048576;
  ushort* wig_bf  = wbf + 3 * 1048576;
  ushort* wo_bf   = wbf + 4 * 1048576;
  ushort* fwi_bf  = wbf + 5 * 1048576;
  ushort* fwg_bf  = wbf + 6 * 1048576;

  const dim3 g8(64, 4);   // 16384/256 x 1024/256

  cvt_weights<<<dim3(1024, 7), 256, 0, stream>>>(
      wr_w, wog_w, wi_w, wig_w, wo_w, ffn_wi_w, ffn_wg_w, wbf);

  // sqrll branch
  rmsnorm_k<true><<<R_ROWS, 256, 0, stream>>>(x, norm_w, y);
  gemm8<0><<<g8, 512, 0, stream>>>(y, wr_bf,  wr_b,  nullptr, nullptr, r,   nullptr);
  gemm8<0><<<g8, 512, 0, stream>>>(y, wog_bf, wog_b, nullptr, nullptr, og,  nullptr);
  gemm8<0><<<g8, 512, 0, stream>>>(y, wig_bf, wig_b, nullptr, nullptr, xgL, nullptr); // ig
  gemm8<2><<<g8, 512, 0, stream>>>(y, wi_bf,  nullptr, nullptr, xgL, xgL, nullptr);   // xg=ig*(y.wi)
  linrec_passA<<<256, 256, 0, stream>>>(xgL, r, cL, cP);
  linrec_passB<<<16, 256, 0, stream>>>(cL, cP, mem, cIn, memoutF);
  linrec_passC<<<256, 256, 0, stream>>>(xgL, r, og, cIn, s);
  cvt_one<<<1024, 256, 0, stream>>>(ffn_wo_w, fwo_bf);     // cL/cP now dead
  gemm8<1><<<g8, 512, 0, stream>>>(s, wo_bf, nullptr, x, nullptr, x1, nullptr);
  // ffn branch
  rmsnorm_k<false><<<R_ROWS, 256, 0, stream>>>(x1, ffnorm_w, z);
  gemm8<0><<<g8, 512, 0, stream>>>(z, fwg_bf, ffn_wg_b, nullptr, nullptr, gf, nullptr);
  gemm8<2><<<g8, 512, 0, stream>>>(z, fwi_bf, nullptr, nullptr, gf, gf, nullptr);     // ff
  gemm8<3><<<g8, 512, 0, stream>>>(gf, fwo_bf, nullptr, nullptr, x1, nullptr, outF);
}

// Round 3
// 556.331 us; speedup vs baseline: 1.3755x; 1.0237x over previous
//
#include <hip/hip_runtime.h>
#include <stdint.h>

// B=4, T=4096, D=1024, M=1024.  I/O fp32.  Round 8: (1) fuse the three
// sigmoid GEMMs (r/og/ig) into one dispatch over stacked [wr|wog|wig]
// (grid 64x12, out/bias selected per bn-group); (2) 16B epilogue stores;
// (3) hoisted staging addresses; (4) linrec TCH=32/NCHUNK=128 (512 blocks,
// 2/CU) with cL/cP/cIn moved to dead d_out scratch.

#define R_ROWS 16384
#define DIM    1024
#define MDIM   1024
#define TSEQ   4096
#define NCHUNK 128
#define TCH    32

typedef __attribute__((ext_vector_type(8))) short  bf16x8;
typedef __attribute__((ext_vector_type(8))) ushort u16x8;
typedef __attribute__((ext_vector_type(4))) float  f32x4;

__device__ __forceinline__ float bf2f(ushort u) {
  union { float f; unsigned int i; } x; x.i = ((unsigned int)u) << 16; return x.f;
}
__device__ __forceinline__ ushort f2bf(float f) {
  union { float f; unsigned int i; } x; x.f = f;
  unsigned int r = x.i + 0x7fffu + ((x.i >> 16) & 1u);
  return (ushort)(r >> 16);
}
__device__ __forceinline__ float sigmoidf_(float x) {
  return 1.0f / (1.0f + __expf(-x));
}
__device__ __forceinline__ void load_lds16(const void* g, void* s) {
  __builtin_amdgcn_global_load_lds(
      (const __attribute__((address_space(1))) void*)g,
      (__attribute__((address_space(3))) void*)s, 16, 0, 0);
}

// ------------- weight pre-convert: 7 matrices of 1M fp32 -> bf16 ------------
// slot order: 0=wr 1=wog 2=wig 3=wi 4=wo 5=ffn_wi 6=ffn_wg   (0..2 contiguous
// for the fused tri-sigmoid GEMM)
__global__ __launch_bounds__(256)
void cvt_weights(const float* __restrict__ w0, const float* __restrict__ w1,
                 const float* __restrict__ w2, const float* __restrict__ w3,
                 const float* __restrict__ w4, const float* __restrict__ w5,
                 const float* __restrict__ w6, ushort* __restrict__ dst)
{
  const float* src;
  switch (blockIdx.y) {
    case 0: src = w0; break; case 1: src = w1; break;
    case 2: src = w2; break; case 3: src = w3; break;
    case 4: src = w4; break; case 5: src = w5; break;
    default: src = w6; break;
  }
  const int i = blockIdx.x * 256 + threadIdx.x;           // [0, 262144)
  const size_t off = (size_t)blockIdx.y * 1048576 + (size_t)i * 4;
  const float4 v = *(const float4*)(src + (size_t)i * 4);
  ushort4 o; o.x = f2bf(v.x); o.y = f2bf(v.y); o.z = f2bf(v.z); o.w = f2bf(v.w);
  *(ushort4*)(dst + off) = o;
}

// single-matrix fp32 -> bf16 (ffn_wo -> ws scratch, region free from start)
__global__ __launch_bounds__(256)
void cvt_one(const float* __restrict__ src, ushort* __restrict__ dst)
{
  const int i = blockIdx.x * 256 + threadIdx.x;           // [0, 262144)
  const float4 v = *(const float4*)(src + (size_t)i * 4);
  ushort4 o; o.x = f2bf(v.x); o.y = f2bf(v.y); o.z = f2bf(v.z); o.w = f2bf(v.w);
  *(ushort4*)(dst + (size_t)i * 4) = o;
}

// ---------------- RMSNorm: one block per row of 1024 -> bf16 out ------------
template<bool IN_F32>
__global__ __launch_bounds__(256)
void rmsnorm_k(const void* __restrict__ xin, const float* __restrict__ w,
               ushort* __restrict__ y)
{
  __shared__ float red[4];
  const int row = blockIdx.x;
  const int tid = threadIdx.x;
  const size_t base = (size_t)row * DIM + tid * 4;
  float v[4];
  if (IN_F32) {
    const float4 xv = *(const float4*)((const float*)xin + base);
    v[0] = xv.x; v[1] = xv.y; v[2] = xv.z; v[3] = xv.w;
  } else {
    const ushort4 xv = *(const ushort4*)((const ushort*)xin + base);
    v[0] = bf2f(xv.x); v[1] = bf2f(xv.y); v[2] = bf2f(xv.z); v[3] = bf2f(xv.w);
  }
  float ss = v[0]*v[0] + v[1]*v[1] + v[2]*v[2] + v[3]*v[3];
  for (int o = 32; o > 0; o >>= 1) ss += __shfl_down(ss, o, 64);
  const int wave = tid >> 6, lane = tid & 63;
  if (lane == 0) red[wave] = ss;
  __syncthreads();
  const float sum = red[0] + red[1] + red[2] + red[3];
  const float scale = rsqrtf(sum * (1.0f / DIM) + 1e-6f);
  const float4 wv = *(const float4*)(w + tid * 4);
  ushort4 o4;
  o4.x = f2bf(v[0] * scale * wv.x);
  o4.y = f2bf(v[1] * scale * wv.y);
  o4.z = f2bf(v[2] * scale * wv.z);
  o4.w = f2bf(v[3] * scale * wv.w);
  *(ushort4*)(y + base) = o4;
}

// ======================= 256^2 8-phase bf16 GEMM ===========================
// C[r,n] = sum_k A[r,k] * W[n,k].  256x256 tile, BK=64, 8 waves (2M x 4N),
// 512 threads, LDS 128 KiB, T2 XOR-swizzle, counted vmcnt(4), setprio.
// Coalesced LDS-transposed epilogue (fp32, 2 half passes, 16B stores).
//
// MODE 0: out bf16 = sigmoid(v + bias[col])
// MODE 1: out bf16 = v + auxf[idx]          (fp32 aux)
// MODE 2: out bf16 = v * bf2f(auxb[idx])    (element-wise, in-place safe)
// MODE 3: out fp32 = v + bf2f(auxb[idx])
// MODE 4: tri-sigmoid — W is stacked [wr|wog|wig] (3072 rows); bn group
//         (bn>>2) selects {outb,bias} / {outb2,bias2} / {outb3,bias3};
//         output column = (bn&3)*256 + local.
template<int MODE>
__global__ __launch_bounds__(512, 2)
void gemm8(const ushort* __restrict__ A, const ushort* __restrict__ W,
           const float* __restrict__ bias, const float* __restrict__ auxf,
           const ushort* __restrict__ auxb, ushort* __restrict__ outb,
           float* __restrict__ outf,
           const float* __restrict__ bias2, const float* __restrict__ bias3,
           ushort* __restrict__ outb2, ushort* __restrict__ outb3)
{
  __shared__ __align__(16) ushort lds[2][2][2][8192]; // [buf][A/B][half][128*64]
  const int tid  = threadIdx.x;
  const int bm = blockIdx.x, bn = blockIdx.y;
  const int wave = tid >> 6, lane = tid & 63;
  const int wm = wave >> 2, wn = wave & 3;            // 2M x 4N waves
  const int quad = lane >> 4, l16 = lane & 15;
  const int axor = l16 & 7;                           // row&7 for all our reads

  const ushort* Ab = A + (size_t)bm * (256 * 1024);
  const ushort* Wb = W + (size_t)bn * (256 * 1024);

  f32x4 acc[8][4];
#pragma unroll
  for (int i = 0; i < 8; ++i)
#pragma unroll
    for (int j = 0; j < 4; ++j) acc[i][j] = (f32x4){0.f, 0.f, 0.f, 0.f};

  // hoisted per-thread staging offsets (2 load slots per half-tile stage)
  const int ci0 = tid, ci1 = tid + 512;
  const size_t gs0 = (size_t)(ci0 >> 3) * 1024 + (size_t)((((ci0 & 7) ^ ((ci0 >> 3) & 7))) << 3);
  const size_t gs1 = (size_t)(ci1 >> 3) * 1024 + (size_t)((((ci1 & 7) ^ ((ci1 >> 3) & 7))) << 3);
  auto stage = [&](const ushort* __restrict__ src, ushort* dst) {
    load_lds16(src + gs0, dst + ci0 * 8);
    load_lds16(src + gs1, dst + ci1 * 8);
  };

  // prologue: kt0 {A0,A1,B0,B1}, kt1 {B0,B1}; vmcnt(4) -> kt0 landed.
  stage(Ab,          &lds[0][0][0][0]); stage(Ab + 131072,      &lds[0][0][1][0]);
  stage(Wb,          &lds[0][1][0][0]); stage(Wb + 131072,      &lds[0][1][1][0]);
  stage(Wb + 64,     &lds[1][1][0][0]); stage(Wb + 131072 + 64, &lds[1][1][1][0]);
  asm volatile("s_waitcnt vmcnt(4)" ::: "memory");
  __builtin_amdgcn_s_barrier();

  for (int ktc = 0; ktc < 16; ++ktc) {
    const int b = ktc & 1;
    const ushort* Ah = &lds[b][0][wm][0];
    const ushort* Bh = &lds[b][1][wn >> 1][0];
    const int brow0 = (wn & 1) * 64;
    bf16x8 bfr[4][2];
#pragma unroll
    for (int q = 0; q < 4; ++q) {
      if (q == 0) {
#pragma unroll
        for (int j = 0; j < 4; ++j)
#pragma unroll
          for (int ks = 0; ks < 2; ++ks)
            bfr[j][ks] = *(const bf16x8*)
                &Bh[(brow0 + j * 16 + l16) * 64 +
                    (((ks * 4 + quad) ^ axor) << 3)];
      }
      bf16x8 af[2][2];
#pragma unroll
      for (int p = 0; p < 2; ++p)
#pragma unroll
        for (int ks = 0; ks < 2; ++ks)
          af[p][ks] = *(const bf16x8*)
              &Ah[((2 * q + p) * 16 + l16) * 64 +
                  (((ks * 4 + quad) ^ axor) << 3)];
      if (q == 0 && ktc + 1 < 16)
        stage(Ab + (ktc + 1) * 64, &lds[(ktc + 1) & 1][0][0][0]);
      if (q == 1 && ktc + 1 < 16)
        stage(Ab + 131072 + (ktc + 1) * 64, &lds[(ktc + 1) & 1][0][1][0]);
      if (q == 2 && ktc + 2 < 16)
        stage(Wb + (ktc + 2) * 64, &lds[ktc & 1][1][0][0]);
      if (q == 3 && ktc + 2 < 16)
        stage(Wb + 131072 + (ktc + 2) * 64, &lds[ktc & 1][1][1][0]);
      __builtin_amdgcn_s_barrier();
      asm volatile("s_waitcnt lgkmcnt(0)" ::: "memory");
      __builtin_amdgcn_s_setprio(1);
#pragma unroll
      for (int p = 0; p < 2; ++p)
#pragma unroll
        for (int j = 0; j < 4; ++j)
#pragma unroll
          for (int ks = 0; ks < 2; ++ks)
            acc[2 * q + p][j] = __builtin_amdgcn_mfma_f32_16x16x32_bf16(
                af[p][ks], bfr[j][ks], acc[2 * q + p][j], 0, 0, 0);
      __builtin_amdgcn_s_setprio(0);
      if (q == 3) {
        if (ktc >= 14) asm volatile("s_waitcnt vmcnt(0)" ::: "memory");
        else           asm volatile("s_waitcnt vmcnt(4)" ::: "memory");
      }
      __builtin_amdgcn_s_barrier();
    }
  }

  // ---------------- coalesced LDS-transposed epilogue ----------------
  float* C = (float*)&lds[0][0][0][0];                // [128][256] fp32
  ushort* ob = outb;
  const float* bp = bias;
  int colbase = bn * 256;
  if (MODE == 4) {
    const int grp = bn >> 2;
    ob = (grp == 0) ? outb : (grp == 1) ? outb2 : outb3;
    bp = (grp == 0) ? bias : (grp == 1) ? bias2 : bias3;
    colbase = (bn & 3) * 256;
  }
#pragma unroll 1
  for (int h = 0; h < 2; ++h) {
    if (wm == h) {
      const int cb = wn * 64;
#pragma unroll
      for (int i = 0; i < 8; ++i)
#pragma unroll
        for (int j = 0; j < 4; ++j)
#pragma unroll
          for (int g = 0; g < 4; ++g) {
            const int rw = i * 16 + quad * 4 + g;
            const int cw = cb + j * 16 + l16;
            C[rw * 256 + (cw ^ (((rw >> 2) & 1) << 4))] = acc[i][j][g];
          }
    }
    __syncthreads();
#pragma unroll 1
    for (int sp = 0; sp < 8; ++sp) {
      const int lin = sp * 4096 + tid * 8;            // 8 elems/thread
      const int row = lin >> 8, c8 = lin & 255;
      const int xr = ((row >> 2) & 1) << 4;
      const int cx = c8 ^ xr;                         // (c8+4)^xr == cx+4
      const float4 vA = *(const float4*)&C[row * 256 + cx];
      const float4 vB = *(const float4*)&C[row * 256 + cx + 4];
      const int rg = bm * 256 + h * 128 + row;
      const size_t gidx = (size_t)rg * 1024 + colbase + c8;
      if (MODE == 0 || MODE == 4) {
        const float4 b0 = *(const float4*)(bp + colbase + c8);
        const float4 b1 = *(const float4*)(bp + colbase + c8 + 4);
        u16x8 o;
        o[0] = f2bf(sigmoidf_(vA.x + b0.x)); o[1] = f2bf(sigmoidf_(vA.y + b0.y));
        o[2] = f2bf(sigmoidf_(vA.z + b0.z)); o[3] = f2bf(sigmoidf_(vA.w + b0.w));
        o[4] = f2bf(sigmoidf_(vB.x + b1.x)); o[5] = f2bf(sigmoidf_(vB.y + b1.y));
        o[6] = f2bf(sigmoidf_(vB.z + b1.z)); o[7] = f2bf(sigmoidf_(vB.w + b1.w));
        *(u16x8*)(ob + gidx) = o;
      } else if (MODE == 1) {
        const float4 a0 = *(const float4*)(auxf + gidx);
        const float4 a1 = *(const float4*)(auxf + gidx + 4);
        u16x8 o;
        o[0] = f2bf(vA.x + a0.x); o[1] = f2bf(vA.y + a0.y);
        o[2] = f2bf(vA.z + a0.z); o[3] = f2bf(vA.w + a0.w);
        o[4] = f2bf(vB.x + a1.x); o[5] = f2bf(vB.y + a1.y);
        o[6] = f2bf(vB.z + a1.z); o[7] = f2bf(vB.w + a1.w);
        *(u16x8*)(ob + gidx) = o;
      } else if (MODE == 2) {
        const u16x8 a8 = *(const u16x8*)(auxb + gidx);
        u16x8 o;
        o[0] = f2bf(vA.x * bf2f(a8[0])); o[1] = f2bf(vA.y * bf2f(a8[1]));
        o[2] = f2bf(vA.z * bf2f(a8[2])); o[3] = f2bf(vA.w * bf2f(a8[3]));
        o[4] = f2bf(vB.x * bf2f(a8[4])); o[5] = f2bf(vB.y * bf2f(a8[5]));
        o[6] = f2bf(vB.z * bf2f(a8[6])); o[7] = f2bf(vB.w * bf2f(a8[7]));
        *(u16x8*)(ob + gidx) = o;
      } else {
        const u16x8 a8 = *(const u16x8*)(auxb + gidx);
        float4 o0, o1;
        o0.x = vA.x + bf2f(a8[0]); o0.y = vA.y + bf2f(a8[1]);
        o0.z = vA.z + bf2f(a8[2]); o0.w = vA.w + bf2f(a8[3]);
        o1.x = vB.x + bf2f(a8[4]); o1.y = vB.y + bf2f(a8[5]);
        o1.z = vB.z + bf2f(a8[6]); o1.w = vB.w + bf2f(a8[7]);
        *(float4*)(outf + gidx) = o0;
        *(float4*)(outf + gidx + 4) = o1;
      }
    }
    if (h == 0) __syncthreads();
  }
}

// ------------- linear recurrence h_t = xg_t + r_t*h_{t-1}, chunked ----------
// TCH=32, NCHUNK=128: 131072 threads -> 512 blocks (2/CU).  4 m per thread.
__global__ __launch_bounds__(256)
void linrec_passA(ushort* __restrict__ xg, const ushort* __restrict__ r,
                  float* __restrict__ cL, float* __restrict__ cP)
{
  const int g = blockIdx.x * 256 + threadIdx.x;   // [0, 131072)
  const int m4 = (g & 255) << 2;
  const int bc = g >> 8;                          // [0, 512)
  const int b = bc >> 7, c = bc & 127;
  const size_t base = ((size_t)(b * TSEQ + c * TCH)) * MDIM + m4;
  float h0 = 0.f, h1 = 0.f, h2 = 0.f, h3 = 0.f;
  float p0 = 1.f, p1 = 1.f, p2 = 1.f, p3 = 1.f;
  for (int t = 0; t < TCH; ++t) {
    const size_t idx = base + (size_t)t * MDIM;
    const ushort4 xv = *(const ushort4*)&xg[idx];
    const ushort4 rv = *(const ushort4*)&r[idx];
    const float r0 = bf2f(rv.x), r1 = bf2f(rv.y), r2 = bf2f(rv.z), r3 = bf2f(rv.w);
    h0 = fmaf(r0, h0, bf2f(xv.x)); p0 *= r0;
    h1 = fmaf(r1, h1, bf2f(xv.y)); p1 *= r1;
    h2 = fmaf(r2, h2, bf2f(xv.z)); p2 *= r2;
    h3 = fmaf(r3, h3, bf2f(xv.w)); p3 *= r3;
    ushort4 o; o.x = f2bf(h0); o.y = f2bf(h1); o.z = f2bf(h2); o.w = f2bf(h3);
    *(ushort4*)&xg[idx] = o;   // local prefix (chunk-start state 0), in place
  }
  const size_t cb = (size_t)c * 4096 + b * MDIM + m4;
  float4 L4; L4.x = h0; L4.y = h1; L4.z = h2; L4.w = h3;
  float4 P4; P4.x = p0; P4.y = p1; P4.z = p2; P4.w = p3;
  *(float4*)&cL[cb] = L4;
  *(float4*)&cP[cb] = P4;
}

__global__ __launch_bounds__(256)
void linrec_passB(const float* __restrict__ cL, const float* __restrict__ cP,
                  const float* __restrict__ mem, float* __restrict__ cIn,
                  float* __restrict__ memout)
{
  const int g = blockIdx.x * 256 + threadIdx.x;   // [0,4096)
  float carry = mem[g];
#pragma unroll 4
  for (int c = 0; c < NCHUNK; ++c) {
    cIn[c * 4096 + g] = carry;
    carry = fmaf(cP[c * 4096 + g], carry, cL[c * 4096 + g]);
  }
  memout[g] = carry;
}

__global__ __launch_bounds__(256)
void linrec_passC(const ushort* __restrict__ L, const ushort* __restrict__ r,
                  const ushort* __restrict__ og, const float* __restrict__ cIn,
                  ushort* __restrict__ s)
{
  const int g = blockIdx.x * 256 + threadIdx.x;   // [0, 131072)
  const int m4 = (g & 255) << 2;
  const int bc = g >> 8;
  const int b = bc >> 7, c = bc & 127;
  const size_t base = ((size_t)(b * TSEQ + c * TCH)) * MDIM + m4;
  const size_t cb = (size_t)c * 4096 + b * MDIM + m4;
  const float4 ci = *(const float4*)&cIn[cb];
  float p0 = 1.f, p1 = 1.f, p2 = 1.f, p3 = 1.f;
  for (int t = 0; t < TCH; ++t) {
    const size_t idx = base + (size_t)t * MDIM;
    const ushort4 rv = *(const ushort4*)&r[idx];
    const ushort4 lv = *(const ushort4*)&L[idx];
    const ushort4 ov = *(const ushort4*)&og[idx];
    p0 *= bf2f(rv.x); p1 *= bf2f(rv.y); p2 *= bf2f(rv.z); p3 *= bf2f(rv.w);
    const float a0 = fmaf(p0, ci.x, bf2f(lv.x));
    const float a1 = fmaf(p1, ci.y, bf2f(lv.y));
    const float a2 = fmaf(p2, ci.z, bf2f(lv.z));
    const float a3 = fmaf(p3, ci.w, bf2f(lv.w));
    ushort4 o;
    o.x = f2bf(a0 / (1.0f + fabsf(a0)) * bf2f(ov.x));
    o.y = f2bf(a1 / (1.0f + fabsf(a1)) * bf2f(ov.y));
    o.z = f2bf(a2 / (1.0f + fabsf(a2)) * bf2f(ov.z));
    o.w = f2bf(a3 / (1.0f + fabsf(a3)) * bf2f(ov.w));
    *(ushort4*)&s[idx] = o;
  }
}

// ---------------- launch ----------------
extern "C" void kernel_launch(void* const* d_in, const int* in_sizes, int n_in,
                              void* d_out, int out_size, void* d_ws, size_t ws_size,
                              hipStream_t stream)
{
  const float* x        = (const float*)d_in[0];
  const float* mem      = (const float*)d_in[1];
  const float* norm_w   = (const float*)d_in[2];
  const float* wr_w     = (const float*)d_in[3];
  const float* wr_b     = (const float*)d_in[4];
  const float* wi_w     = (const float*)d_in[5];
  const float* wig_w    = (const float*)d_in[6];
  const float* wig_b    = (const float*)d_in[7];
  const float* wog_w    = (const float*)d_in[8];
  const float* wog_b    = (const float*)d_in[9];
  const float* wo_w     = (const float*)d_in[10];
  const float* ffnorm_w = (const float*)d_in[11];
  const float* ffn_wi_w = (const float*)d_in[12];
  const float* ffn_wg_w = (const float*)d_in[13];
  const float* ffn_wg_b = (const float*)d_in[14];
  const float* ffn_wo_w = (const float*)d_in[15];
  float* outF = (float*)d_out;

  // d_out scratch (dead until final GEMM / passB):
  ushort* xgL  = (ushort*)d_out;                        // [0,32MB): ig -> xg -> L
  ushort* wbf  = (ushort*)((char*)d_out + 33554432ULL); // [32,46MB): 7x bf16 W
  float*  cL   = (float*)((char*)d_out + 48234496ULL);  // [46,48MB)
  float*  cP   = (float*)((char*)d_out + 50331648ULL);  // [48,50MB)
  float*  cIn  = (float*)((char*)d_out + 52428800ULL);  // [50,52MB)
  float*  memoutF = outF + 16777216;                    // mem_out fp32

  // ws (~97MB):
  char* ws = (char*)d_ws;
  ushort* y   = (ushort*)(ws);                 // 32MB bf16: y -> s -> gf/ff
  ushort* r   = (ushort*)(ws + 33554432ULL);   // 32MB bf16: r -> z
  ushort* og  = (ushort*)(ws + 67108864ULL);   // 32MB bf16: og -> x1
  ushort* fwo_bf = (ushort*)(ws + 100663296ULL); // 2MB bf16 ffn_wo
  ushort* s   = y;
  ushort* x1  = og;
  ushort* z   = r;
  ushort* gf  = y;                             // ffn gate -> ff (in-place)

  // bf16 weight slots (1M elems each): 0=wr 1=wog 2=wig 3=wi 4=wo 5=ffn_wi 6=ffn_wg
  ushort* wr_bf   = wbf + 0 * 1048576;   // also the stacked [wr|wog|wig] base
  ushort* wi_bf   = wbf + 3 * 1048576;
  ushort* wo_bf   = wbf + 4 * 1048576;
  ushort* fwi_bf  = wbf + 5 * 1048576;
  ushort* fwg_bf  = wbf + 6 * 1048576;

  const dim3 g8(64, 4);    // single-output GEMMs
  const dim3 g83(64, 12);  // fused tri-sigmoid

  cvt_weights<<<dim3(1024, 7), 256, 0, stream>>>(
      wr_w, wog_w, wig_w, wi_w, wo_w, ffn_wi_w, ffn_wg_w, wbf);
  cvt_one<<<1024, 256, 0, stream>>>(ffn_wo_w, fwo_bf);

  // sqrll branch
  rmsnorm_k<true><<<R_ROWS, 256, 0, stream>>>(x, norm_w, y);
  // fused: r = sig(y.wr+b), og = sig(y.wog+b), ig = sig(y.wig+b) -> xgL
  gemm8<4><<<g83, 512, 0, stream>>>(y, wr_bf, wr_b, nullptr, nullptr, r, nullptr,
                                    wog_b, wig_b, og, xgL);
  // xg = ig * (y.wi)
  gemm8<2><<<g8, 512, 0, stream>>>(y, wi_bf, nullptr, nullptr, xgL, xgL, nullptr,
                                   nullptr, nullptr, nullptr, nullptr);
  linrec_passA<<<512, 256, 0, stream>>>(xgL, r, cL, cP);
  linrec_passB<<<16, 256, 0, stream>>>(cL, cP, mem, cIn, memoutF);
  linrec_passC<<<512, 256, 0, stream>>>(xgL, r, og, cIn, s);
  gemm8<1><<<g8, 512, 0, stream>>>(s, wo_bf, nullptr, x, nullptr, x1, nullptr,
                                   nullptr, nullptr, nullptr, nullptr);
  // ffn branch
  rmsnorm_k<false><<<R_ROWS, 256, 0, stream>>>(x1, ffnorm_w, z);
  gemm8<0><<<g8, 512, 0, stream>>>(z, fwg_bf, ffn_wg_b, nullptr, nullptr, gf, nullptr,
                                   nullptr, nullptr, nullptr, nullptr);
  gemm8<2><<<g8, 512, 0, stream>>>(z, fwi_bf, nullptr, nullptr, gf, gf, nullptr,
                                   nullptr, nullptr, nullptr, nullptr);
  gemm8<3><<<g8, 512, 0, stream>>>(gf, fwo_bf, nullptr, nullptr, x1, nullptr, outF,
                                   nullptr, nullptr, nullptr, nullptr);
}

// Round 4
// 530.051 us; speedup vs baseline: 1.4437x; 1.0496x over previous
//
#include <hip/hip_runtime.h>
#include <stdint.h>

// B=4, T=4096, D=1024, M=1024.  I/O fp32.  Round 9:
// (1) K-loop re-scheduled: ONE barrier per phase (4/K-tile instead of 8),
//     A triple-buffered (LDS 160 KiB = 96K A + 64K B), stages at
//     q0:B1(kt+1) q1:A0(kt+2) q2:A1(kt+2) q3:B0(kt+2), counted vmcnt(6)
//     at q3 BEFORE the barrier (cross-wave staging visibility), vmcnt(0)
//     at kt==14, nothing at kt==15.  Wave skew within a phase overlaps
//     one wave's ds_reads with another's MFMA.
// (2) Interleaved-gated weights: [wig;wi] and [ffn_wg;ffn_wi] stacked
//     per-128-col-group so one block computes gate+value for the same
//     output columns -> writes xg / ff directly.  Sqrll pre-linrec is ONE
//     64x16 dispatch (r, og, xg); the two MODE-2 passes are eliminated.

#define R_ROWS 16384
#define DIM    1024
#define MDIM   1024
#define TSEQ   4096
#define NCHUNK 128
#define TCH    32

typedef __attribute__((ext_vector_type(8))) short  bf16x8;
typedef __attribute__((ext_vector_type(8))) ushort u16x8;
typedef __attribute__((ext_vector_type(4))) float  f32x4;

__device__ __forceinline__ float bf2f(ushort u) {
  union { float f; unsigned int i; } x; x.i = ((unsigned int)u) << 16; return x.f;
}
__device__ __forceinline__ ushort f2bf(float f) {
  union { float f; unsigned int i; } x; x.f = f;
  unsigned int r = x.i + 0x7fffu + ((x.i >> 16) & 1u);
  return (ushort)(r >> 16);
}
__device__ __forceinline__ float sigmoidf_(float x) {
  return 1.0f / (1.0f + __expf(-x));
}
__device__ __forceinline__ void load_lds16(const void* g, void* s) {
  __builtin_amdgcn_global_load_lds(
      (const __attribute__((address_space(1))) void*)g,
      (__attribute__((address_space(3))) void*)s, 16, 0, 0);
}

// LDS map (flat, 163840 B): A slot s(0..2) half h at AOFF, B slot s(0..1).
#define AOFF(s,h) ((((s)*2)+(h))*8192)
#define BOFF(s,h) (49152 + (((s)*2)+(h))*8192)

// ------------- weight pre-convert -> bf16, with interleave remap -----------
// dst layout (elems): [0,1M) wr | [1M,2M) wog | [2M,4M) wig_wi interleaved
// (per 128-col group g: rows g*256..+127 = wig, +128..+255 = wi) |
// [4M,5M) wo | [5M,7M) ffn_wg/ffn_wi interleaved.
__global__ __launch_bounds__(256)
void cvt_weights(const float* __restrict__ w0, const float* __restrict__ w1,
                 const float* __restrict__ w2, const float* __restrict__ w3,
                 const float* __restrict__ w4, const float* __restrict__ w5,
                 const float* __restrict__ w6, ushort* __restrict__ dst)
{
  const float* src; size_t base; int il;
  switch (blockIdx.y) {
    case 0: src = w0; base = 0;       il = 0; break;  // wr
    case 1: src = w1; base = 1048576; il = 0; break;  // wog
    case 2: src = w2; base = 2097152; il = 1; break;  // wig (gate)
    case 3: src = w3; base = 2097152; il = 2; break;  // wi  (value)
    case 4: src = w4; base = 5242880; il = 1; break;  // ffn_wg
    case 5: src = w5; base = 5242880; il = 2; break;  // ffn_wi
    default: src = w6; base = 4194304; il = 0; break; // wo
  }
  const int i = blockIdx.x * 256 + threadIdx.x;           // [0, 262144)
  const size_t e = (size_t)i * 4;
  size_t off;
  if (il == 0) off = base + e;
  else {
    const int row = (int)(e >> 10), col = (int)(e & 1023);
    const int nr = ((row >> 7) << 8) + (row & 127) + (il == 2 ? 128 : 0);
    off = base + (size_t)nr * 1024 + col;
  }
  const float4 v = *(const float4*)(src + e);
  ushort4 o; o.x = f2bf(v.x); o.y = f2bf(v.y); o.z = f2bf(v.z); o.w = f2bf(v.w);
  *(ushort4*)(dst + off) = o;
}

// single-matrix fp32 -> bf16 (ffn_wo -> ws scratch)
__global__ __launch_bounds__(256)
void cvt_one(const float* __restrict__ src, ushort* __restrict__ dst)
{
  const int i = blockIdx.x * 256 + threadIdx.x;
  const float4 v = *(const float4*)(src + (size_t)i * 4);
  ushort4 o; o.x = f2bf(v.x); o.y = f2bf(v.y); o.z = f2bf(v.z); o.w = f2bf(v.w);
  *(ushort4*)(dst + (size_t)i * 4) = o;
}

// ---------------- RMSNorm: one block per row of 1024 -> bf16 out ------------
template<bool IN_F32>
__global__ __launch_bounds__(256)
void rmsnorm_k(const void* __restrict__ xin, const float* __restrict__ w,
               ushort* __restrict__ y)
{
  __shared__ float red[4];
  const int row = blockIdx.x;
  const int tid = threadIdx.x;
  const size_t base = (size_t)row * DIM + tid * 4;
  float v[4];
  if (IN_F32) {
    const float4 xv = *(const float4*)((const float*)xin + base);
    v[0] = xv.x; v[1] = xv.y; v[2] = xv.z; v[3] = xv.w;
  } else {
    const ushort4 xv = *(const ushort4*)((const ushort*)xin + base);
    v[0] = bf2f(xv.x); v[1] = bf2f(xv.y); v[2] = bf2f(xv.z); v[3] = bf2f(xv.w);
  }
  float ss = v[0]*v[0] + v[1]*v[1] + v[2]*v[2] + v[3]*v[3];
  for (int o = 32; o > 0; o >>= 1) ss += __shfl_down(ss, o, 64);
  const int wave = tid >> 6, lane = tid & 63;
  if (lane == 0) red[wave] = ss;
  __syncthreads();
  const float sum = red[0] + red[1] + red[2] + red[3];
  const float scale = rsqrtf(sum * (1.0f / DIM) + 1e-6f);
  const float4 wv = *(const float4*)(w + tid * 4);
  ushort4 o4;
  o4.x = f2bf(v[0] * scale * wv.x);
  o4.y = f2bf(v[1] * scale * wv.y);
  o4.z = f2bf(v[2] * scale * wv.z);
  o4.w = f2bf(v[3] * scale * wv.w);
  *(ushort4*)(y + base) = o4;
}

// ======================= 256^2 1-barrier/phase bf16 GEMM ====================
// C[r,n] = sum_k A[r,k] * W[n,k].  256x256 tile, BK=64, 8 waves (2M x 4N),
// 512 threads.  T2 XOR-swizzle on staging+reads.  A triple-buffered,
// B double-buffered (160 KiB LDS).  Per phase: {reads; stage; [vmcnt@q3];
// BAR; lgkm(0); setprio(1); 16 MFMA; setprio(0)} — no trailing barrier.
//
// MODE 1: out bf16 = v + auxf[idx]            (fp32 aux)
// MODE 3: out fp32 = v + bf2f(auxb[idx])
// MODE 5: gated interleaved: W panel rows 0-127 gate, 128-255 value;
//         out bf16[cols bn*128+128) ] = value * sigmoid(gate + bias)
// MODE 6: bn>>2==0: r=sig(+bias); ==1: og=sig(+bias2)->outb2;
//         bn>=8: gated as MODE5 with bias3 -> outb3, cols (bn-8)*128.
template<int MODE>
__global__ __launch_bounds__(512, 2)
void gemm8(const ushort* __restrict__ A, const ushort* __restrict__ W,
           const float* __restrict__ bias, const float* __restrict__ auxf,
           const ushort* __restrict__ auxb, ushort* __restrict__ outb,
           float* __restrict__ outf,
           const float* __restrict__ bias2, const float* __restrict__ bias3,
           ushort* __restrict__ outb2, ushort* __restrict__ outb3)
{
  __shared__ __align__(16) ushort lds[81920];   // 160 KiB
  const int tid  = threadIdx.x;
  const int bm = blockIdx.x, bn = blockIdx.y;
  const int wave = tid >> 6, lane = tid & 63;
  const int wm = wave >> 2, wn = wave & 3;            // 2M x 4N waves
  const int quad = lane >> 4, l16 = lane & 15;
  const int axor = l16 & 7;

  const ushort* Ab = A + (size_t)bm * (256 * 1024);
  const ushort* Wb = W + (size_t)bn * (256 * 1024);

  f32x4 acc[8][4];
#pragma unroll
  for (int i = 0; i < 8; ++i)
#pragma unroll
    for (int j = 0; j < 4; ++j) acc[i][j] = (f32x4){0.f, 0.f, 0.f, 0.f};

  // hoisted per-thread staging offsets (2 loads per half-tile stage)
  const int ci0 = tid, ci1 = tid + 512;
  const size_t gs0 = (size_t)(ci0 >> 3) * 1024 + (size_t)(((ci0 & 7) ^ ((ci0 >> 3) & 7)) << 3);
  const size_t gs1 = (size_t)(ci1 >> 3) * 1024 + (size_t)(((ci1 & 7) ^ ((ci1 >> 3) & 7)) << 3);
  auto stage = [&](const ushort* __restrict__ src, int loff) {
    load_lds16(src + gs0, &lds[loff + ci0 * 8]);
    load_lds16(src + gs1, &lds[loff + ci1 * 8]);
  };

  // prologue: A(0), B(0), A(1), B0(1)  (7 half-stages = 14 loads);
  // vmcnt(6) keeps A(1)+B0(1) in flight, drains A(0)+B(0).
  stage(Ab,               AOFF(0,0));
  stage(Ab + 131072,      AOFF(0,1));
  stage(Wb,               BOFF(0,0));
  stage(Wb + 131072,      BOFF(0,1));
  stage(Ab + 64,          AOFF(1,0));
  stage(Ab + 131072 + 64, AOFF(1,1));
  stage(Wb + 64,          BOFF(1,0));
  asm volatile("s_waitcnt vmcnt(6)" ::: "memory");
  __builtin_amdgcn_s_barrier();

  int kt3 = 0;                                        // kt % 3
  for (int kt = 0; kt < 16; ++kt) {
    const ushort* Ah = &lds[AOFF(kt3, wm)];
    const ushort* Bh = &lds[BOFF(kt & 1, wn >> 1)];
    const int kt2s = (kt3 >= 1) ? kt3 - 1 : 2;        // (kt+2) % 3
    const int brow0 = (wn & 1) * 64;
    bf16x8 bfr[4][2];
#pragma unroll
    for (int q = 0; q < 4; ++q) {
      if (q == 0) {
#pragma unroll
        for (int j = 0; j < 4; ++j)
#pragma unroll
          for (int ks = 0; ks < 2; ++ks)
            bfr[j][ks] = *(const bf16x8*)
                &Bh[(brow0 + j * 16 + l16) * 64 +
                    (((ks * 4 + quad) ^ axor) << 3)];
      }
      bf16x8 af[2][2];
#pragma unroll
      for (int p = 0; p < 2; ++p)
#pragma unroll
        for (int ks = 0; ks < 2; ++ks)
          af[p][ks] = *(const bf16x8*)
              &Ah[((2 * q + p) * 16 + l16) * 64 +
                  (((ks * 4 + quad) ^ axor) << 3)];
      if (q == 0 && kt + 1 < 16)
        stage(Wb + 131072 + (kt + 1) * 64, BOFF((kt + 1) & 1, 1)); // B1(kt+1)
      if (q == 1 && kt + 2 < 16)
        stage(Ab + (kt + 2) * 64,          AOFF(kt2s, 0));         // A0(kt+2)
      if (q == 2 && kt + 2 < 16)
        stage(Ab + 131072 + (kt + 2) * 64, AOFF(kt2s, 1));         // A1(kt+2)
      if (q == 3) {
        if (kt + 2 < 16)
          stage(Wb + (kt + 2) * 64,        BOFF(kt & 1, 0));       // B0(kt+2)
        // counted drain BEFORE the barrier -> cross-wave visibility of the
        // next K-tile's staged data.  Steady state: 8 outstanding, keep 6
        // (A0/A1/B0 of kt+2).  kt==14: skips leave only B1(15) -> full drain.
        if (kt < 14)       asm volatile("s_waitcnt vmcnt(6)" ::: "memory");
        else if (kt == 14) asm volatile("s_waitcnt vmcnt(0)" ::: "memory");
      }
      __builtin_amdgcn_s_barrier();
      asm volatile("s_waitcnt lgkmcnt(0)" ::: "memory");
      __builtin_amdgcn_s_setprio(1);
#pragma unroll
      for (int p = 0; p < 2; ++p)
#pragma unroll
        for (int j = 0; j < 4; ++j)
#pragma unroll
          for (int ks = 0; ks < 2; ++ks)
            acc[2 * q + p][j] = __builtin_amdgcn_mfma_f32_16x16x32_bf16(
                af[p][ks], bfr[j][ks], acc[2 * q + p][j], 0, 0, 0);
      __builtin_amdgcn_s_setprio(0);
      // no trailing barrier: waves may skew into the next phase's reads.
    }
    kt3 = (kt3 == 2) ? 0 : kt3 + 1;
  }

  // ---------------- coalesced LDS-transposed epilogue ----------------
  // barrier first: every wave executed its q3 lgkm(0) before arriving, so
  // all K-loop ds_reads are complete; no global_load_lds in flight (kt==14
  // drained to 0, kt==15 staged nothing).
  __builtin_amdgcn_s_barrier();
  float* C = (float*)lds;                             // [128][256] fp32
  const bool gated = (MODE == 5) || (MODE == 6 && bn >= 8);
#pragma unroll 1
  for (int h = 0; h < 2; ++h) {
    if (wm == h) {
      const int cb = wn * 64;
#pragma unroll
      for (int i = 0; i < 8; ++i)
#pragma unroll
        for (int j = 0; j < 4; ++j)
#pragma unroll
          for (int g = 0; g < 4; ++g) {
            const int rw = i * 16 + quad * 4 + g;
            const int cw = cb + j * 16 + l16;
            C[rw * 256 + (cw ^ (((rw >> 2) & 1) << 4))] = acc[i][j][g];
          }
    }
    __syncthreads();
    if (gated) {
      const int outcol = (MODE == 6) ? (bn - 8) * 128 : bn * 128;
      const float* bp = (MODE == 6) ? bias3 : bias;
      ushort* ob = (MODE == 6) ? outb3 : outb;
#pragma unroll 1
      for (int sp = 0; sp < 4; ++sp) {
        const int lin = sp * 4096 + tid * 8;          // [0, 16384)
        const int row = lin >> 7, c8 = lin & 127;
        const int xr = ((row >> 2) & 1) << 4;
        const int cg = c8 ^ xr;                       // gate cols (0..127)
        const int cv = (c8 + 128) ^ xr;               // value cols (128..255)
        const float4 gA = *(const float4*)&C[row * 256 + cg];
        const float4 gB = *(const float4*)&C[row * 256 + cg + 4];
        const float4 vA = *(const float4*)&C[row * 256 + cv];
        const float4 vB = *(const float4*)&C[row * 256 + cv + 4];
        const float4 b0 = *(const float4*)(bp + outcol + c8);
        const float4 b1 = *(const float4*)(bp + outcol + c8 + 4);
        const int rg = bm * 256 + h * 128 + row;
        const size_t gidx = (size_t)rg * 1024 + outcol + c8;
        u16x8 o;
        o[0] = f2bf(vA.x * sigmoidf_(gA.x + b0.x));
        o[1] = f2bf(vA.y * sigmoidf_(gA.y + b0.y));
        o[2] = f2bf(vA.z * sigmoidf_(gA.z + b0.z));
        o[3] = f2bf(vA.w * sigmoidf_(gA.w + b0.w));
        o[4] = f2bf(vB.x * sigmoidf_(gB.x + b1.x));
        o[5] = f2bf(vB.y * sigmoidf_(gB.y + b1.y));
        o[6] = f2bf(vB.z * sigmoidf_(gB.z + b1.z));
        o[7] = f2bf(vB.w * sigmoidf_(gB.w + b1.w));
        *(u16x8*)(ob + gidx) = o;
      }
    } else {
#pragma unroll 1
      for (int sp = 0; sp < 8; ++sp) {
        const int lin = sp * 4096 + tid * 8;
        const int row = lin >> 8, c8 = lin & 255;
        const int xr = ((row >> 2) & 1) << 4;
        const int cx = c8 ^ xr;
        const float4 vA = *(const float4*)&C[row * 256 + cx];
        const float4 vB = *(const float4*)&C[row * 256 + cx + 4];
        const int rg = bm * 256 + h * 128 + row;
        if (MODE == 6) {
          const int grp = bn >> 2;                    // 0 -> r, 1 -> og
          ushort* ob = grp ? outb2 : outb;
          const float* bp = grp ? bias2 : bias;
          const int colbase = (bn & 3) * 256;
          const size_t gidx = (size_t)rg * 1024 + colbase + c8;
          const float4 b0 = *(const float4*)(bp + colbase + c8);
          const float4 b1 = *(const float4*)(bp + colbase + c8 + 4);
          u16x8 o;
          o[0] = f2bf(sigmoidf_(vA.x + b0.x)); o[1] = f2bf(sigmoidf_(vA.y + b0.y));
          o[2] = f2bf(sigmoidf_(vA.z + b0.z)); o[3] = f2bf(sigmoidf_(vA.w + b0.w));
          o[4] = f2bf(sigmoidf_(vB.x + b1.x)); o[5] = f2bf(sigmoidf_(vB.y + b1.y));
          o[6] = f2bf(sigmoidf_(vB.z + b1.z)); o[7] = f2bf(sigmoidf_(vB.w + b1.w));
          *(u16x8*)(ob + gidx) = o;
        } else if (MODE == 1) {
          const size_t gidx = (size_t)rg * 1024 + bn * 256 + c8;
          const float4 a0 = *(const float4*)(auxf + gidx);
          const float4 a1 = *(const float4*)(auxf + gidx + 4);
          u16x8 o;
          o[0] = f2bf(vA.x + a0.x); o[1] = f2bf(vA.y + a0.y);
          o[2] = f2bf(vA.z + a0.z); o[3] = f2bf(vA.w + a0.w);
          o[4] = f2bf(vB.x + a1.x); o[5] = f2bf(vB.y + a1.y);
          o[6] = f2bf(vB.z + a1.z); o[7] = f2bf(vB.w + a1.w);
          *(u16x8*)(outb + gidx) = o;
        } else {                                      // MODE 3
          const size_t gidx = (size_t)rg * 1024 + bn * 256 + c8;
          const u16x8 a8 = *(const u16x8*)(auxb + gidx);
          float4 o0, o1;
          o0.x = vA.x + bf2f(a8[0]); o0.y = vA.y + bf2f(a8[1]);
          o0.z = vA.z + bf2f(a8[2]); o0.w = vA.w + bf2f(a8[3]);
          o1.x = vB.x + bf2f(a8[4]); o1.y = vB.y + bf2f(a8[5]);
          o1.z = vB.z + bf2f(a8[6]); o1.w = vB.w + bf2f(a8[7]);
          *(float4*)(outf + gidx) = o0;
          *(float4*)(outf + gidx + 4) = o1;
        }
      }
    }
    if (h == 0) __syncthreads();
  }
}

// ------------- linear recurrence h_t = xg_t + r_t*h_{t-1}, chunked ----------
__global__ __launch_bounds__(256)
void linrec_passA(ushort* __restrict__ xg, const ushort* __restrict__ r,
                  float* __restrict__ cL, float* __restrict__ cP)
{
  const int g = blockIdx.x * 256 + threadIdx.x;   // [0, 131072)
  const int m4 = (g & 255) << 2;
  const int bc = g >> 8;                          // [0, 512)
  const int b = bc >> 7, c = bc & 127;
  const size_t base = ((size_t)(b * TSEQ + c * TCH)) * MDIM + m4;
  float h0 = 0.f, h1 = 0.f, h2 = 0.f, h3 = 0.f;
  float p0 = 1.f, p1 = 1.f, p2 = 1.f, p3 = 1.f;
  for (int t = 0; t < TCH; ++t) {
    const size_t idx = base + (size_t)t * MDIM;
    const ushort4 xv = *(const ushort4*)&xg[idx];
    const ushort4 rv = *(const ushort4*)&r[idx];
    const float r0 = bf2f(rv.x), r1 = bf2f(rv.y), r2 = bf2f(rv.z), r3 = bf2f(rv.w);
    h0 = fmaf(r0, h0, bf2f(xv.x)); p0 *= r0;
    h1 = fmaf(r1, h1, bf2f(xv.y)); p1 *= r1;
    h2 = fmaf(r2, h2, bf2f(xv.z)); p2 *= r2;
    h3 = fmaf(r3, h3, bf2f(xv.w)); p3 *= r3;
    ushort4 o; o.x = f2bf(h0); o.y = f2bf(h1); o.z = f2bf(h2); o.w = f2bf(h3);
    *(ushort4*)&xg[idx] = o;
  }
  const size_t cb = (size_t)c * 4096 + b * MDIM + m4;
  float4 L4; L4.x = h0; L4.y = h1; L4.z = h2; L4.w = h3;
  float4 P4; P4.x = p0; P4.y = p1; P4.z = p2; P4.w = p3;
  *(float4*)&cL[cb] = L4;
  *(float4*)&cP[cb] = P4;
}

__global__ __launch_bounds__(256)
void linrec_passB(const float* __restrict__ cL, const float* __restrict__ cP,
                  const float* __restrict__ mem, float* __restrict__ cIn,
                  float* __restrict__ memout)
{
  const int g = blockIdx.x * 256 + threadIdx.x;   // [0,4096)
  float carry = mem[g];
#pragma unroll 4
  for (int c = 0; c < NCHUNK; ++c) {
    cIn[c * 4096 + g] = carry;
    carry = fmaf(cP[c * 4096 + g], carry, cL[c * 4096 + g]);
  }
  memout[g] = carry;
}

__global__ __launch_bounds__(256)
void linrec_passC(const ushort* __restrict__ L, const ushort* __restrict__ r,
                  const ushort* __restrict__ og, const float* __restrict__ cIn,
                  ushort* __restrict__ s)
{
  const int g = blockIdx.x * 256 + threadIdx.x;   // [0, 131072)
  const int m4 = (g & 255) << 2;
  const int bc = g >> 8;
  const int b = bc >> 7, c = bc & 127;
  const size_t base = ((size_t)(b * TSEQ + c * TCH)) * MDIM + m4;
  const size_t cb = (size_t)c * 4096 + b * MDIM + m4;
  const float4 ci = *(const float4*)&cIn[cb];
  float p0 = 1.f, p1 = 1.f, p2 = 1.f, p3 = 1.f;
  for (int t = 0; t < TCH; ++t) {
    const size_t idx = base + (size_t)t * MDIM;
    const ushort4 rv = *(const ushort4*)&r[idx];
    const ushort4 lv = *(const ushort4*)&L[idx];
    const ushort4 ov = *(const ushort4*)&og[idx];
    p0 *= bf2f(rv.x); p1 *= bf2f(rv.y); p2 *= bf2f(rv.z); p3 *= bf2f(rv.w);
    const float a0 = fmaf(p0, ci.x, bf2f(lv.x));
    const float a1 = fmaf(p1, ci.y, bf2f(lv.y));
    const float a2 = fmaf(p2, ci.z, bf2f(lv.z));
    const float a3 = fmaf(p3, ci.w, bf2f(lv.w));
    ushort4 o;
    o.x = f2bf(a0 / (1.0f + fabsf(a0)) * bf2f(ov.x));
    o.y = f2bf(a1 / (1.0f + fabsf(a1)) * bf2f(ov.y));
    o.z = f2bf(a2 / (1.0f + fabsf(a2)) * bf2f(ov.z));
    o.w = f2bf(a3 / (1.0f + fabsf(a3)) * bf2f(ov.w));
    *(ushort4*)&s[idx] = o;
  }
}

// ---------------- launch ----------------
extern "C" void kernel_launch(void* const* d_in, const int* in_sizes, int n_in,
                              void* d_out, int out_size, void* d_ws, size_t ws_size,
                              hipStream_t stream)
{
  const float* x        = (const float*)d_in[0];
  const float* mem      = (const float*)d_in[1];
  const float* norm_w   = (const float*)d_in[2];
  const float* wr_w     = (const float*)d_in[3];
  const float* wr_b     = (const float*)d_in[4];
  const float* wi_w     = (const float*)d_in[5];
  const float* wig_w    = (const float*)d_in[6];
  const float* wig_b    = (const float*)d_in[7];
  const float* wog_w    = (const float*)d_in[8];
  const float* wog_b    = (const float*)d_in[9];
  const float* wo_w     = (const float*)d_in[10];
  const float* ffnorm_w = (const float*)d_in[11];
  const float* ffn_wi_w = (const float*)d_in[12];
  const float* ffn_wg_w = (const float*)d_in[13];
  const float* ffn_wg_b = (const float*)d_in[14];
  const float* ffn_wo_w = (const float*)d_in[15];
  float* outF = (float*)d_out;

  // d_out scratch (dead until final GEMM / passB):
  ushort* xgL  = (ushort*)d_out;                        // [0,32MB): xg -> L
  ushort* wbf  = (ushort*)((char*)d_out + 33554432ULL); // [32,46MB): 7M bf16 W
  float*  cL   = (float*)((char*)d_out + 48234496ULL);  // [46,48MB)
  float*  cP   = (float*)((char*)d_out + 50331648ULL);  // [48,50MB)
  float*  cIn  = (float*)((char*)d_out + 52428800ULL);  // [50,52MB)
  float*  memoutF = outF + 16777216;                    // mem_out fp32

  // ws (~97MB):
  char* ws = (char*)d_ws;
  ushort* y   = (ushort*)(ws);                 // 32MB bf16: y -> s -> gf/ff
  ushort* r   = (ushort*)(ws + 33554432ULL);   // 32MB bf16: r -> z
  ushort* og  = (ushort*)(ws + 67108864ULL);   // 32MB bf16: og -> x1
  ushort* fwo_bf = (ushort*)(ws + 100663296ULL); // 2MB bf16 ffn_wo
  ushort* s   = y;
  ushort* x1  = og;
  ushort* z   = r;
  ushort* gf  = y;                             // ffn ff

  cvt_weights<<<dim3(1024, 7), 256, 0, stream>>>(
      wr_w, wog_w, wig_w, wi_w, ffn_wg_w, ffn_wi_w, wo_w, wbf);
  cvt_one<<<1024, 256, 0, stream>>>(ffn_wo_w, fwo_bf);

  // sqrll branch: one dispatch -> r, og, xg
  rmsnorm_k<true><<<R_ROWS, 256, 0, stream>>>(x, norm_w, y);
  gemm8<6><<<dim3(64, 16), 512, 0, stream>>>(
      y, wbf, wr_b, nullptr, nullptr, r, nullptr, wog_b, wig_b, og, xgL);
  linrec_passA<<<512, 256, 0, stream>>>(xgL, r, cL, cP);
  linrec_passB<<<16, 256, 0, stream>>>(cL, cP, mem, cIn, memoutF);
  linrec_passC<<<512, 256, 0, stream>>>(xgL, r, og, cIn, s);
  gemm8<1><<<dim3(64, 4), 512, 0, stream>>>(
      s, wbf + 4194304, nullptr, x, nullptr, x1, nullptr,
      nullptr, nullptr, nullptr, nullptr);
  // ffn branch: gated in one dispatch -> ff
  rmsnorm_k<false><<<R_ROWS, 256, 0, stream>>>(x1, ffnorm_w, z);
  gemm8<5><<<dim3(64, 8), 512, 0, stream>>>(
      z, wbf + 5242880, ffn_wg_b, nullptr, nullptr, gf, nullptr,
      nullptr, nullptr, nullptr, nullptr);
  gemm8<3><<<dim3(64, 4), 512, 0, stream>>>(
      gf, fwo_bf, nullptr, nullptr, x1, nullptr, outF,
      nullptr, nullptr, nullptr, nullptr);
}